// Round 7
// baseline (319.553 us; speedup 1.0000x reference)
//
#include <hip/hip_runtime.h>
#include <hip/hip_fp16.h>
#include <math.h>

#define N_NODES    100000
#define N_PATHS    1600000
#define PATH_SZ    3
#define IN_SZ      64
#define HID        32
#define EMB_STRIDE 96          // PATH_SZ * HID (halves)
#define EPS_F      1e-4f

#define SCAN_TPB   256
#define SCAN_IPT   8
#define SCAN_CHUNK (SCAN_TPB * SCAN_IPT)                        // 2048
#define SCAN_NB    ((N_NODES + SCAN_CHUNK - 1) / SCAN_CHUNK)   // 49

// ---- static device scratch ----
__device__ __half g_embh[(size_t)N_NODES * EMB_STRIDE];  // 19.2 MB fp16
__device__ float  g_M[HID * HID];                        // gram^{-1/2}
__device__ int    g_offs[N_NODES];
__device__ int    g_bsum[SCAN_NB];
__device__ int    g_boff[SCAN_NB];

// ---------------- prefix-sum of kernel_size -> g_offs ----------------
__global__ __launch_bounds__(SCAN_TPB) void k_scan1(const int* __restrict__ ksz) {
    __shared__ int red[SCAN_TPB];
    int b = blockIdx.x, t = threadIdx.x;
    int base = b * SCAN_CHUNK + t * SCAN_IPT;
    int s = 0;
#pragma unroll
    for (int u = 0; u < SCAN_IPT; u++) {
        int idx = base + u;
        if (idx < N_NODES) s += ksz[idx];
    }
    red[t] = s;
    __syncthreads();
    for (int d = SCAN_TPB >> 1; d > 0; d >>= 1) {
        if (t < d) red[t] += red[t + d];
        __syncthreads();
    }
    if (t == 0) g_bsum[b] = red[0];
}

__global__ void k_scan2() {
    if (threadIdx.x == 0) {
        int run = 0;
        for (int b = 0; b < SCAN_NB; b++) { g_boff[b] = run; run += g_bsum[b]; }
    }
}

__global__ __launch_bounds__(SCAN_TPB) void k_scan3(const int* __restrict__ ksz) {
    __shared__ int sc[SCAN_TPB];
    int b = blockIdx.x, t = threadIdx.x;
    int base = b * SCAN_CHUNK + t * SCAN_IPT;
    int v[SCAN_IPT];
    int s = 0;
#pragma unroll
    for (int u = 0; u < SCAN_IPT; u++) {
        int idx = base + u;
        v[u] = (idx < N_NODES) ? ksz[idx] : 0;
        s += v[u];
    }
    sc[t] = s;
    __syncthreads();
    for (int d = 1; d < SCAN_TPB; d <<= 1) {
        int a = (t >= d) ? sc[t - d] : 0;
        __syncthreads();
        sc[t] += a;
        __syncthreads();
    }
    int incl = sc[t];
    int run = g_boff[b] + (incl - s);
#pragma unroll
    for (int u = 0; u < SCAN_IPT; u++) {
        int idx = base + u;
        if (idx < N_NODES) g_offs[idx] = run;
        run += v[u];
    }
}

// ---------------- gram + coupled Newton-Schulz -> g_M (single block) ----------------
// G = I + E, off-diag ~ e^-4 => spectrum in ~[0.97,1.56] => 6 NS iters to fp32 precision.
struct ShJ {
    float w[96 * 65];    // padded weight copy
    float Y[32 * 33];
    float Z[32 * 33];
    float P[32 * 33];
};

__global__ __launch_bounds__(256) void k_ns(const float* __restrict__ W) {
    __shared__ ShJ sh;
    int t = threadIdx.x;

    for (int idx = t; idx < 96 * 64; idx += 256) {
        int r = idx >> 6, c = idx & 63;
        sh.w[r * 65 + c] = W[idx];
    }
    __syncthreads();
#pragma unroll
    for (int u = 0; u < 4; u++) {
        int e = t * 4 + u;
        int h = e >> 5, g = e & 31;
        float d = 0.f;
        for (int pi = 0; pi < 3; pi++) {
            const float* r0 = &sh.w[(h * 3 + pi) * 65];
            const float* r1 = &sh.w[(g * 3 + pi) * 65];
#pragma unroll
            for (int i = 0; i < 64; i++) d = fmaf(r0[i], r1[i], d);
        }
        sh.Y[h * 33 + g] = __expf(fmaf(d, 4.0f / 3.0f, -4.0f));
        sh.Z[h * 33 + g] = (h == g) ? 1.0f : 0.0f;
    }
    __syncthreads();
    // coupled NS: P = Z*Y; T = (3I-P)/2; Y <- Y*T; Z <- T*Z
    for (int it = 0; it < 6; it++) {
#pragma unroll
        for (int u = 0; u < 4; u++) {
            int e = t * 4 + u;
            int i = e >> 5, j = e & 31;
            float p = 0.f;
#pragma unroll
            for (int k = 0; k < 32; k++)
                p = fmaf(sh.Z[i * 33 + k], sh.Y[k * 33 + j], p);
            sh.P[i * 33 + j] = p;
        }
        __syncthreads();
        float U[4], V[4];
#pragma unroll
        for (int u = 0; u < 4; u++) {
            int e = t * 4 + u;
            int i = e >> 5, j = e & 31;
            float su = 0.f, sv = 0.f;
#pragma unroll
            for (int k = 0; k < 32; k++) {
                float Tkj = -0.5f * sh.P[k * 33 + j]; if (k == j) Tkj += 1.5f;
                float Tik = -0.5f * sh.P[i * 33 + k]; if (i == k) Tik += 1.5f;
                su = fmaf(sh.Y[i * 33 + k], Tkj, su);
                sv = fmaf(Tik, sh.Z[k * 33 + j], sv);
            }
            U[u] = su; V[u] = sv;
        }
        __syncthreads();
#pragma unroll
        for (int u = 0; u < 4; u++) {
            int e = t * 4 + u;
            int i = e >> 5, j = e & 31;
            sh.Y[i * 33 + j] = U[u];
            sh.Z[i * 33 + j] = V[u];
        }
        __syncthreads();
    }
#pragma unroll
    for (int u = 0; u < 4; u++) {
        int e = t * 4 + u;
        g_M[e] = sh.Z[(e >> 5) * 33 + (e & 31)];
    }
}

// ---------------- emb GEMM: wave = (64 nodes, one p); p wave-uniform ----------------
#define EMB_WAVES ((((N_NODES + 63) / 64) * 3))          // 4689
#define EMB_BLOCKS ((EMB_WAVES + 3) / 4)                 // 1173

__global__ __launch_bounds__(256) void k_emb(const float* __restrict__ feat,
                                             const float* __restrict__ W) {
    int t = threadIdx.x;
    int w = t >> 6, lane = t & 63;
    int wg = blockIdx.x * 4 + w;
    if (wg >= EMB_WAVES) return;
    int p = wg % 3;                        // wave-uniform
    int node = (wg / 3) * 64 + lane;
    if (node >= N_NODES) return;

    float x[64];
    const float4* f4 = reinterpret_cast<const float4*>(feat + (size_t)node * 64);
#pragma unroll
    for (int c = 0; c < 16; c++) {
        float4 v = f4[c];
        x[c * 4 + 0] = v.x; x[c * 4 + 1] = v.y; x[c * 4 + 2] = v.z; x[c * 4 + 3] = v.w;
    }
    float ssum = 0.f;
#pragma unroll
    for (int i = 0; i < 64; i++) ssum = fmaf(x[i], x[i], ssum);
    float inv = 1.0f / fmaxf(sqrtf(ssum), EPS_F);

    __half hv[32];
#pragma unroll
    for (int h = 0; h < HID; h++) {        // FULL unroll: hv[] stays in registers
        const float* wr = W + ((h * 3 + p) << 6);   // wave-uniform -> scalar loads
        float a = 0.f;
#pragma unroll
        for (int i = 0; i < 64; i++) a = fmaf(x[i], wr[i], a);
        hv[h] = __float2half(a * inv);
    }
    // 64 B contiguous store of this p-slice
    const int4* src = reinterpret_cast<const int4*>(hv);
    int4* dst = reinterpret_cast<int4*>(&g_embh[(size_t)node * EMB_STRIDE + p * HID]);
#pragma unroll
    for (int c = 0; c < 4; c++) dst[c] = src[c];
}

// ---------------- gather + kappa + segment-sum + whiten (wave per node) ----------------
__global__ __launch_bounds__(256) void k_pool(const int* __restrict__ paths,
                                              const int* __restrict__ ksz,
                                              float* __restrict__ out) {
    __shared__ float Ml[HID * HID];
    for (int idx = threadIdx.x; idx < HID * HID; idx += 256) Ml[idx] = g_M[idx];
    __syncthreads();

    int lane = threadIdx.x & 63;
    int half = lane >> 5;
    int j = lane & 31;
    int node = blockIdx.x * 4 + (threadIdx.x >> 6);   // grid exactly N_NODES/4 blocks
    const __half* eb = g_embh;

    int off = g_offs[node];
    int ks  = ksz[node];
    float pooled = 0.f;

    if (ks == 16) {
        // fast path: half-wave handles 8 paths, 2 chunks x 4 paths (12 gathers in flight)
        const int* pb = paths + (size_t)(off + (half << 3)) * 3;
#pragma unroll
        for (int c = 0; c < 2; c++) {
            int ix[12];
#pragma unroll
            for (int u = 0; u < 12; u++) ix[u] = pb[c * 12 + u];
            __half v0[4], v1[4], v2[4];
#pragma unroll
            for (int q = 0; q < 4; q++) {
                v0[q] = eb[(size_t)ix[3 * q + 0] * EMB_STRIDE + j];
                v1[q] = eb[(size_t)ix[3 * q + 1] * EMB_STRIDE + HID + j];
                v2[q] = eb[(size_t)ix[3 * q + 2] * EMB_STRIDE + 2 * HID + j];
            }
#pragma unroll
            for (int q = 0; q < 4; q++) {
                float e = __half2float(v0[q]) + __half2float(v1[q]) + __half2float(v2[q]);
                pooled += __expf(fmaf(e, 4.0f / 3.0f, -4.0f));
            }
        }
    } else {
        // generic path (exact repeat/segment semantics for any ks)
        for (int pi = half; pi < ks; pi += 2) {
            size_t pp = (size_t)(off + pi) * 3;
            int i0 = paths[pp + 0], i1 = paths[pp + 1], i2 = paths[pp + 2];
            float e = __half2float(eb[(size_t)i0 * EMB_STRIDE + j])
                    + __half2float(eb[(size_t)i1 * EMB_STRIDE + HID + j])
                    + __half2float(eb[(size_t)i2 * EMB_STRIDE + 2 * HID + j]);
            pooled += __expf(fmaf(e, 4.0f / 3.0f, -4.0f));
        }
    }

    pooled += __shfl_xor(pooled, 32);       // combine the two half-waves
    // whiten: out[node][j] = sum_k pooled[k] * M[k][j]
    float o = 0.f;
#pragma unroll
    for (int k = 0; k < 32; k++)
        o = fmaf(__shfl(pooled, k), Ml[k * 32 + j], o);
    if (half == 0) out[(size_t)node * HID + j] = o;
}

extern "C" void kernel_launch(void* const* d_in, const int* in_sizes, int n_in,
                              void* d_out, int out_size, void* d_ws, size_t ws_size,
                              hipStream_t stream) {
    const float* feat  = (const float*)d_in[0];
    const int*   paths = (const int*)d_in[1];
    const int*   ksz   = (const int*)d_in[2];
    const float* W     = (const float*)d_in[3];
    float*       out   = (float*)d_out;

    k_scan1<<<SCAN_NB, SCAN_TPB, 0, stream>>>(ksz);
    k_scan2<<<1, 64, 0, stream>>>();
    k_scan3<<<SCAN_NB, SCAN_TPB, 0, stream>>>(ksz);

    k_ns<<<1, 256, 0, stream>>>(W);
    k_emb<<<EMB_BLOCKS, 256, 0, stream>>>(feat, W);

    k_pool<<<N_NODES / 4, 256, 0, stream>>>(paths, ksz, out);
}